// Round 1
// baseline (1842.589 us; speedup 1.0000x reference)
//
#include <hip/hip_runtime.h>
#include <math.h>

static constexpr int B_ = 16;
static constexpr int N_ = 1024;
static constexpr int K_ = 20;

// ---------------- per-point squared norm ----------------
template<int C>
__global__ __launch_bounds__(256) void xx_kernel(const float* __restrict__ h,
                                                 float* __restrict__ xx) {
  int i = blockIdx.x * 256 + threadIdx.x;
  if (i >= B_ * N_) return;
  int b = i >> 10, n = i & 1023;
  const float* hb = h + (size_t)b * C * N_ + n;
  float s = 0.f;
  #pragma unroll 4
  for (int c = 0; c < C; ++c) { float v = hb[(size_t)c * N_]; s = fmaf(v, v, s); }
  xx[i] = s;
}

// ---------------- fused distance + top-20 selection ----------------
// block = (b, 16 rows). dist row tile kept in LDS; selection = iterative
// wave argmax with lower-index tie-break (matches jax.lax.top_k set).
template<int C>
__global__ __launch_bounds__(256) void knn_kernel(const float* __restrict__ h,
                                                  const float* __restrict__ xx,
                                                  int* __restrict__ idxg) {
  __shared__ float dist_s[16][N_];     // 64 KB
  __shared__ float xm_s[C][128];       // <= 64 KB
  __shared__ float xn_s[C][16];        // <= 8 KB
  const int b  = blockIdx.y;
  const int n0 = blockIdx.x * 16;
  const int tid = threadIdx.x;
  const float* hb = h + (size_t)b * C * N_;
  for (int i = tid; i < C * 16; i += 256) {
    int c = i >> 4, r = i & 15;
    xn_s[c][r] = hb[(size_t)c * N_ + n0 + r];
  }
  const int lane = tid & 63;
  const int wv   = tid >> 6;
  const int mmb  = lane * 2;     // 2 columns per lane within a 128-wide chunk
  const int rb   = wv * 4;       // 4 rows per wave
  float xxn[4];
  #pragma unroll
  for (int rr = 0; rr < 4; ++rr) xxn[rr] = xx[b * N_ + n0 + rb + rr];

  for (int ch = 0; ch < 8; ++ch) {
    const int m0 = ch * 128;
    __syncthreads();                       // protect xm reuse (and xn on ch=0)
    for (int i = tid; i < C * 128; i += 256) {
      int c = i >> 7, mm = i & 127;
      xm_s[c][mm] = hb[(size_t)c * N_ + m0 + mm];
    }
    __syncthreads();
    float acc0[4] = {0.f, 0.f, 0.f, 0.f};
    float acc1[4] = {0.f, 0.f, 0.f, 0.f};
    for (int c = 0; c < C; ++c) {
      float2 xm2 = *(const float2*)&xm_s[c][mmb];
      #pragma unroll
      for (int rr = 0; rr < 4; ++rr) {
        float xnv = xn_s[c][rb + rr];
        acc0[rr] = fmaf(xnv, xm2.x, acc0[rr]);
        acc1[rr] = fmaf(xnv, xm2.y, acc1[rr]);
      }
    }
    // neg_d2 = -((xx_n - 2*inner) + xx_m)  (mirrors reference fp32 rounding)
    float xxm0 = xx[b * N_ + m0 + mmb];
    float xxm1 = xx[b * N_ + m0 + mmb + 1];
    #pragma unroll
    for (int rr = 0; rr < 4; ++rr) {
      dist_s[rb + rr][m0 + mmb]     = -(fmaf(-2.f, acc0[rr], xxn[rr]) + xxm0);
      dist_s[rb + rr][m0 + mmb + 1] = -(fmaf(-2.f, acc1[rr], xxn[rr]) + xxm1);
    }
  }
  __syncthreads();
  // selection: each wave selects on the 4 rows it computed
  for (int rr = 0; rr < 4; ++rr) {
    const int r = rb + rr;
    float v[16];
    #pragma unroll
    for (int t = 0; t < 16; ++t) v[t] = dist_s[r][lane + (t << 6)];
    unsigned sel = 0;
    const int outbase = (b * N_ + n0 + r) * K_;
    for (int it = 0; it < K_; ++it) {
      float bv = -3.4e38f; int bt = 16;
      #pragma unroll
      for (int t = 0; t < 16; ++t) {       // ascending t + strict '>' keeps lowest idx on tie
        bool avail = ((sel >> t) & 1u) == 0u;
        if (avail && v[t] > bv) { bv = v[t]; bt = t; }
      }
      int bidx = (bt < 16) ? (lane + (bt << 6)) : 0x7FFFFFFF;
      #pragma unroll
      for (int off = 32; off > 0; off >>= 1) {
        float ov = __shfl_xor(bv, off);
        int   oi = __shfl_xor(bidx, off);
        if (ov > bv || (ov == bv && oi < bidx)) { bv = ov; bidx = oi; }
      }
      if (bidx != 0x7FFFFFFF && (bidx & 63) == lane) sel |= 1u << (bidx >> 6);
      if (lane == 0) idxg[outbase + it] = bidx;
    }
  }
}

// ---------------- u = W1*h, w = (W2-W1)*h ----------------
// out layout (B, N, CO). grid: x = N/128, y = (CO/64)*2 (even=u, odd=w), z = B
template<int C, int CO>
__global__ __launch_bounds__(256) void gemm_uw_kernel(const float* __restrict__ h,
    const float* __restrict__ W, float* __restrict__ ubuf, float* __restrict__ wbuf) {
  __shared__ float hs[C][128];
  __shared__ float Ws[64][C + 1];          // +1 pad: kill 32-way bank conflict
  const int b  = blockIdx.z;
  const int n0 = blockIdx.x * 128;
  const int which = blockIdx.y & 1;
  const int o0 = (blockIdx.y >> 1) * 64;
  const int tid = threadIdx.x;
  for (int i = tid; i < 64 * C; i += 256) {
    int o = i / C, c = i % C;
    const float* wr = W + (size_t)(o0 + o) * (2 * C);
    float w1 = wr[c];
    Ws[o][c] = which ? (wr[C + c] - w1) : w1;
  }
  const float* hb = h + (size_t)b * C * N_ + n0;
  for (int i = tid; i < C * 128; i += 256) {
    int c = i >> 7, nn = i & 127;
    hs[c][nn] = hb[(size_t)c * N_ + nn];
  }
  __syncthreads();
  const int ob = (tid & 15) * 4;
  const int nb = (tid >> 4) * 8;
  float acc[8][4];
  #pragma unroll
  for (int i = 0; i < 8; ++i)
    #pragma unroll
    for (int j = 0; j < 4; ++j) acc[i][j] = 0.f;
  for (int c = 0; c < C; ++c) {
    float hv[8];
    *(float4*)&hv[0] = *(const float4*)&hs[c][nb];
    *(float4*)&hv[4] = *(const float4*)&hs[c][nb + 4];
    float w0 = Ws[ob][c], w1 = Ws[ob + 1][c], w2 = Ws[ob + 2][c], w3 = Ws[ob + 3][c];
    #pragma unroll
    for (int i = 0; i < 8; ++i) {
      acc[i][0] = fmaf(hv[i], w0, acc[i][0]);
      acc[i][1] = fmaf(hv[i], w1, acc[i][1]);
      acc[i][2] = fmaf(hv[i], w2, acc[i][2]);
      acc[i][3] = fmaf(hv[i], w3, acc[i][3]);
    }
  }
  float* out = (which ? wbuf : ubuf) + ((size_t)(b * N_ + n0 + nb)) * CO + o0 + ob;
  #pragma unroll
  for (int i = 0; i < 8; ++i) {
    float4 v4; v4.x = acc[i][0]; v4.y = acc[i][1]; v4.z = acc[i][2]; v4.w = acc[i][3];
    *(float4*)(out + (size_t)i * CO) = v4;
  }
}

// ---------------- gather pass: per-(o,n) max/min over k + fp64 stats ----------------
// block = (b, 32-channel tile, n-split). u[b][:, tile] staged whole in LDS (128 KB).
template<int CO, int NSPLIT>
__global__ __launch_bounds__(256) void passA_kernel(const float* __restrict__ ubuf,
    const float* __restrict__ wbuf, const int* __restrict__ idxg,
    float* __restrict__ Mx, float* __restrict__ Mn, double* __restrict__ stats) {
  __shared__ float us[N_][32];             // 128 KB, gather reads conflict-free (o fastest)
  const int b = blockIdx.y;
  const int otile = blockIdx.x / NSPLIT;
  const int ns    = blockIdx.x % NSPLIT;
  const int o0 = otile * 32;
  constexpr int NSUB = N_ / NSPLIT;
  const int nstart = ns * NSUB;
  const int tid = threadIdx.x;
  const float* ub = ubuf + (size_t)b * N_ * CO + o0;
  for (int i = tid; i < N_ * 32; i += 256) {
    int n = i >> 5, o = i & 31;
    us[n][o] = ub[(size_t)n * CO + o];
  }
  __syncthreads();
  const int o = tid & 31, ng = tid >> 5;
  double s_y = 0.0, s_y2 = 0.0;
  const size_t bnc = (size_t)b * N_ * CO;
  for (int n = nstart + ng; n < nstart + NSUB; n += 8) {
    const int* ip = idxg + (size_t)(b * N_ + n) * K_;
    int js[20];
    #pragma unroll
    for (int q = 0; q < 5; ++q) {
      int4 t4 = ((const int4*)ip)[q];
      js[q * 4 + 0] = t4.x; js[q * 4 + 1] = t4.y;
      js[q * 4 + 2] = t4.z; js[q * 4 + 3] = t4.w;
    }
    float mx = -3.4e38f, mn = 3.4e38f, s1 = 0.f, s2 = 0.f;
    #pragma unroll
    for (int k = 0; k < 20; ++k) {
      float v = us[js[k]][o];
      mx = fmaxf(mx, v); mn = fminf(mn, v);
      s1 += v; s2 = fmaf(v, v, s2);
    }
    float wvv = wbuf[bnc + (size_t)n * CO + o0 + o];
    // y = u_j + w_n:  sum_k y = s1 + K*w ; sum_k y^2 = s2 + 2*w*s1 + K*w^2
    s_y  += (double)s1 + 20.0 * (double)wvv;
    s_y2 += (double)s2 + 2.0 * (double)wvv * (double)s1 + 20.0 * (double)wvv * (double)wvv;
    Mx[bnc + (size_t)n * CO + o0 + o] = mx;
    Mn[bnc + (size_t)n * CO + o0 + o] = mn;
  }
  __syncthreads();                          // us dead: reuse as reduction scratch
  double* sc = (double*)&us[0][0];
  sc[(o * 8 + ng) * 2]     = s_y;
  sc[(o * 8 + ng) * 2 + 1] = s_y2;
  __syncthreads();
  if (tid < 32) {
    double a = 0.0, c2 = 0.0;
    #pragma unroll
    for (int g = 0; g < 8; ++g) { a += sc[(tid * 8 + g) * 2]; c2 += sc[(tid * 8 + g) * 2 + 1]; }
    atomicAdd(&stats[(o0 + tid) * 2],     a);
    atomicAdd(&stats[(o0 + tid) * 2 + 1], c2);
  }
}

// ---------------- BN + LeakyReLU + (implicit max_k) + transpose to (B,C,N) ----------------
template<int CO>
__global__ __launch_bounds__(256) void passB_kernel(const float* __restrict__ Mx,
    const float* __restrict__ Mn, const float* __restrict__ wbuf,
    const double* __restrict__ stats, const float* __restrict__ gam,
    const float* __restrict__ bet, float* __restrict__ hout) {
  __shared__ float T[CO][65];
  __shared__ float a_s[CO], c_s[CO];
  const int b = blockIdx.y, n0 = blockIdx.x * 64;
  const int tid = threadIdx.x;
  const double CNT = (double)B_ * N_ * K_;
  for (int oo = tid; oo < CO; oo += 256) {
    double m  = stats[oo * 2] / CNT;
    double vv = stats[oo * 2 + 1] / CNT - m * m;
    float a = gam[oo] * rsqrtf((float)vv + 1e-5f);
    a_s[oo] = a;
    c_s[oo] = bet[oo] - a * (float)m;
  }
  __syncthreads();
  const size_t base = (size_t)(b * N_ + n0) * CO;
  for (int i = tid; i < 64 * CO; i += 256) {
    int nn = i / CO, oo = i % CO;
    float a = a_s[oo];
    size_t off = base + (size_t)nn * CO + oo;
    float selv = (a >= 0.f) ? Mx[off] : Mn[off];    // max_k commutes through monotone BN+LReLU
    float z = fmaf(a, selv + wbuf[off], c_s[oo]);
    T[oo][nn] = (z >= 0.f) ? z : 0.2f * z;
  }
  __syncthreads();
  float* hb = hout + (size_t)b * CO * N_ + n0;
  for (int i = tid; i < 64 * CO; i += 256) {
    int oo = i >> 6, nn = i & 63;
    hb[(size_t)oo * N_ + nn] = T[oo][nn];
  }
}

// ---------------- final layer: BN + LReLU + max over (n,k) ----------------
__global__ __launch_bounds__(256) void final_kernel(const float* __restrict__ Mx,
    const float* __restrict__ Mn, const float* __restrict__ wbuf,
    const double* __restrict__ stats, const float* __restrict__ gam,
    const float* __restrict__ bet, float* __restrict__ out) {
  const int b = blockIdx.x, o = threadIdx.x;   // 256 threads = CO
  const double CNT = (double)B_ * N_ * K_;
  double m  = stats[o * 2] / CNT;
  double vv = stats[o * 2 + 1] / CNT - m * m;
  float a = gam[o] * rsqrtf((float)vv + 1e-5f);
  float c = bet[o] - a * (float)m;
  const float* mp = ((a >= 0.f) ? Mx : Mn) + (size_t)b * N_ * 256 + o;
  const float* wp = wbuf + (size_t)b * N_ * 256 + o;
  float best = -3.4e38f;
  for (int n = 0; n < N_; ++n) {
    float z = fmaf(a, mp[(size_t)n * 256] + wp[(size_t)n * 256], c);
    z = (z >= 0.f) ? z : 0.2f * z;
    best = fmaxf(best, z);
  }
  out[b * 256 + o] = best;
}

__global__ void zero_stats(double* p) {
  int i = blockIdx.x * 256 + threadIdx.x;
  if (i < 2048) p[i] = 0.0;
}

extern "C" void kernel_launch(void* const* d_in, const int* in_sizes, int n_in,
                              void* d_out, int out_size, void* d_ws, size_t ws_size,
                              hipStream_t stream) {
  (void)in_sizes; (void)n_in; (void)out_size; (void)ws_size;
  const float* x  = (const float*)d_in[0];
  const float* W0 = (const float*)d_in[1];
  const float* g0 = (const float*)d_in[2];
  const float* b0 = (const float*)d_in[3];
  const float* W1 = (const float*)d_in[4];
  const float* g1 = (const float*)d_in[5];
  const float* b1 = (const float*)d_in[6];
  const float* W2 = (const float*)d_in[7];
  const float* g2 = (const float*)d_in[8];
  const float* b2 = (const float*)d_in[9];
  const float* W3 = (const float*)d_in[10];
  const float* g3 = (const float*)d_in[11];
  const float* b3 = (const float*)d_in[12];

  // workspace layout (~81.3 MB)
  float* ws  = (float*)d_ws;
  float* u   = ws;                               // 16*1024*256
  float* w   = u  + (size_t)B_ * N_ * 256;
  float* Mx  = w  + (size_t)B_ * N_ * 256;
  float* Mn  = Mx + (size_t)B_ * N_ * 256;
  float* h0b = Mn + (size_t)B_ * N_ * 256;       // (B,<=128,N) ping
  float* h1b = h0b + (size_t)B_ * 128 * N_;      // pong
  float* xxv = h1b + (size_t)B_ * 128 * N_;      // B*N norms
  int*   idx = (int*)(xxv + B_ * N_);            // B*N*K
  double* stats = (double*)(idx + (size_t)B_ * N_ * K_);  // 4 * 512 doubles (8B-aligned)

  zero_stats<<<8, 256, 0, stream>>>(stats);

  // Layer 0: C=4, CO=64
  xx_kernel<4><<<B_ * N_ / 256, 256, 0, stream>>>(x, xxv);
  knn_kernel<4><<<dim3(64, B_), 256, 0, stream>>>(x, xxv, idx);
  gemm_uw_kernel<4, 64><<<dim3(8, 2, B_), 256, 0, stream>>>(x, W0, u, w);
  passA_kernel<64, 8><<<dim3(16, B_), 256, 0, stream>>>(u, w, idx, Mx, Mn, stats);
  passB_kernel<64><<<dim3(16, B_), 256, 0, stream>>>(Mx, Mn, w, stats, g0, b0, h0b);

  // Layer 1: C=64, CO=64
  xx_kernel<64><<<B_ * N_ / 256, 256, 0, stream>>>(h0b, xxv);
  knn_kernel<64><<<dim3(64, B_), 256, 0, stream>>>(h0b, xxv, idx);
  gemm_uw_kernel<64, 64><<<dim3(8, 2, B_), 256, 0, stream>>>(h0b, W1, u, w);
  passA_kernel<64, 8><<<dim3(16, B_), 256, 0, stream>>>(u, w, idx, Mx, Mn, stats + 512);
  passB_kernel<64><<<dim3(16, B_), 256, 0, stream>>>(Mx, Mn, w, stats + 512, g1, b1, h1b);

  // Layer 2: C=64, CO=128
  xx_kernel<64><<<B_ * N_ / 256, 256, 0, stream>>>(h1b, xxv);
  knn_kernel<64><<<dim3(64, B_), 256, 0, stream>>>(h1b, xxv, idx);
  gemm_uw_kernel<64, 128><<<dim3(8, 4, B_), 256, 0, stream>>>(h1b, W2, u, w);
  passA_kernel<128, 4><<<dim3(16, B_), 256, 0, stream>>>(u, w, idx, Mx, Mn, stats + 1024);
  passB_kernel<128><<<dim3(16, B_), 256, 0, stream>>>(Mx, Mn, w, stats + 1024, g2, b2, h0b);

  // Layer 3: C=128, CO=256
  xx_kernel<128><<<B_ * N_ / 256, 256, 0, stream>>>(h0b, xxv);
  knn_kernel<128><<<dim3(64, B_), 256, 0, stream>>>(h0b, xxv, idx);
  gemm_uw_kernel<128, 256><<<dim3(8, 8, B_), 256, 0, stream>>>(h0b, W3, u, w);
  passA_kernel<256, 2><<<dim3(16, B_), 256, 0, stream>>>(u, w, idx, Mx, Mn, stats + 1536);
  final_kernel<<<B_, 256, 0, stream>>>(Mx, Mn, w, stats + 1536, g3, b3, (float*)d_out);
}

// Round 2
// 1237.998 us; speedup vs baseline: 1.4884x; 1.4884x over previous
//
#include <hip/hip_runtime.h>
#include <math.h>

static constexpr int B_ = 16;
static constexpr int N_ = 1024;
static constexpr int K_ = 20;

// ---------------- per-point squared norm ----------------
template<int C>
__global__ __launch_bounds__(256) void xx_kernel(const float* __restrict__ h,
                                                 float* __restrict__ xx) {
  int i = blockIdx.x * 256 + threadIdx.x;
  if (i >= B_ * N_) return;
  int b = i >> 10, n = i & 1023;
  const float* hb = h + (size_t)b * C * N_ + n;
  float s = 0.f;
  #pragma unroll 4
  for (int c = 0; c < C; ++c) { float v = hb[(size_t)c * N_]; s = fmaf(v, v, s); }
  xx[i] = s;
}

// ---------------- fused distance + top-20 selection (register-resident) -------
// block = (b, 16 rows), 4 waves x 4 rows. Lane holds 16 distance values in regs
// (cols = ch*128 + j*64 + lane). Per-lane bitonic sort (desc) once, then 20
// rounds of 64-lane butterfly argmax with O(1) per-lane candidate + shift-pop.
template<int C>
__global__ __launch_bounds__(256) void knn_kernel(const float* __restrict__ h,
                                                  const float* __restrict__ xx,
                                                  int* __restrict__ idxg) {
  constexpr int CC = (C < 64) ? C : 64;
  __shared__ float xm_s[CC][128];      // <= 32 KB
  __shared__ float xn_s[C][16];        // <= 8 KB
  const int b  = blockIdx.y;
  const int n0 = blockIdx.x * 16;
  const int tid = threadIdx.x;
  const int lane = tid & 63;
  const int wv   = tid >> 6;
  const int rb   = wv * 4;
  const float* hb = h + (size_t)b * C * N_;
  const float* xxb = xx + b * N_;

  for (int i = tid; i < C * 16; i += 256) {
    int c = i >> 4, r = i & 15;
    xn_s[c][r] = hb[(size_t)c * N_ + n0 + r];
  }
  float xxn[4];
  #pragma unroll
  for (int rr = 0; rr < 4; ++rr) xxn[rr] = xxb[n0 + rb + rr];

  float val[4][16];   // val[row][t], t = ch*2 + j, col = ch*128 + j*64 + lane
  #pragma unroll 1
  for (int ch = 0; ch < 8; ++ch) {
    const int m0 = ch * 128;
    float acc0[4] = {0.f, 0.f, 0.f, 0.f};
    float acc1[4] = {0.f, 0.f, 0.f, 0.f};
    #pragma unroll 1
    for (int cc0 = 0; cc0 < C; cc0 += CC) {
      __syncthreads();
      for (int i = tid; i < CC * 128; i += 256) {
        int c = i >> 7, mm = i & 127;
        xm_s[c][mm] = hb[(size_t)(cc0 + c) * N_ + m0 + mm];
      }
      __syncthreads();
      for (int c = 0; c < CC; ++c) {
        float x0 = xm_s[c][lane];         // 2 lanes/bank: conflict-free
        float x1 = xm_s[c][64 + lane];
        float4 xn4 = *(const float4*)&xn_s[cc0 + c][rb];  // broadcast b128
        float xnv[4] = {xn4.x, xn4.y, xn4.z, xn4.w};
        #pragma unroll
        for (int rr = 0; rr < 4; ++rr) {
          acc0[rr] = fmaf(xnv[rr], x0, acc0[rr]);
          acc1[rr] = fmaf(xnv[rr], x1, acc1[rr]);
        }
      }
    }
    // neg_d2 = -((xx_n - 2*inner) + xx_m)  (same fp32 rounding as reference path)
    float xxm0 = xxb[m0 + lane];
    float xxm1 = xxb[m0 + 64 + lane];
    #pragma unroll
    for (int rr = 0; rr < 4; ++rr) {
      val[rr][2 * ch]     = -(fmaf(-2.f, acc0[rr], xxn[rr]) + xxm0);
      val[rr][2 * ch + 1] = -(fmaf(-2.f, acc1[rr], xxn[rr]) + xxm1);
    }
  }

  // -------- selection: 2 pairs of rows, each pair's chains interleaved --------
  #pragma unroll
  for (int pr = 0; pr < 2; ++pr) {
    unsigned colA[16], colB[16];
    float va[16], vb[16];
    #pragma unroll
    for (int t = 0; t < 16; ++t) {
      unsigned col = (unsigned)((t >> 1) * 128 + (t & 1) * 64 + lane);
      colA[t] = col; colB[t] = col;
      va[t] = val[2 * pr][t];
      vb[t] = val[2 * pr + 1][t];
    }
    // bitonic sort, descending by value (ties within lane: arbitrary)
    #pragma unroll
    for (int k = 2; k <= 16; k <<= 1) {
      #pragma unroll
      for (int j = k >> 1; j > 0; j >>= 1) {
        #pragma unroll
        for (int i = 0; i < 16; ++i) {
          int l = i ^ j;
          if (l > i) {
            bool up = (i & k) == 0;
            {
              bool cnd = up ? (va[i] < va[l]) : (va[i] > va[l]);
              float tv = va[i]; unsigned tc = colA[i];
              va[i]   = cnd ? va[l]   : tv;  colA[i] = cnd ? colA[l] : tc;
              va[l]   = cnd ? tv      : va[l]; colA[l] = cnd ? tc    : colA[l];
            }
            {
              bool cnd = up ? (vb[i] < vb[l]) : (vb[i] > vb[l]);
              float tv = vb[i]; unsigned tc = colB[i];
              vb[i]   = cnd ? vb[l]   : tv;  colB[i] = cnd ? colB[l] : tc;
              vb[l]   = cnd ? tv      : vb[l]; colB[l] = cnd ? tc    : colB[l];
            }
          }
        }
      }
    }
    const int outA = (b * N_ + n0 + rb + 2 * pr) * K_;
    const int outB = outA + K_;
    #pragma unroll 1
    for (int it = 0; it < K_; ++it) {
      float bvA = va[0]; unsigned bcA = colA[0];
      float bvB = vb[0]; unsigned bcB = colB[0];
      #pragma unroll
      for (int off = 32; off >= 1; off >>= 1) {
        float ovA = __shfl_xor(bvA, off); unsigned ocA = (unsigned)__shfl_xor((int)bcA, off);
        float ovB = __shfl_xor(bvB, off); unsigned ocB = (unsigned)__shfl_xor((int)bcB, off);
        bool tA = (ovA > bvA) || (ovA == bvA && ocA < bcA);
        bvA = tA ? ovA : bvA; bcA = tA ? ocA : bcA;
        bool tB = (ovB > bvB) || (ovB == bvB && ocB < bcB);
        bvB = tB ? ovB : bvB; bcB = tB ? ocB : bcB;
      }
      if (lane == 0) {
        idxg[outA + it] = (int)bcA;
        idxg[outB + it] = (int)bcB;
      }
      if (colA[0] == bcA) {   // winner lane pops its head
        #pragma unroll
        for (int t = 0; t < 15; ++t) { va[t] = va[t + 1]; colA[t] = colA[t + 1]; }
        va[15] = -3.4e38f; colA[15] = 0xFFFFFFFFu;
      }
      if (colB[0] == bcB) {
        #pragma unroll
        for (int t = 0; t < 15; ++t) { vb[t] = vb[t + 1]; colB[t] = colB[t + 1]; }
        vb[15] = -3.4e38f; colB[15] = 0xFFFFFFFFu;
      }
    }
  }
}

// ---------------- u = W1*h, w = (W2-W1)*h ----------------
// out layout (B, N, CO). grid: x = N/128, y = (CO/64)*2 (even=u, odd=w), z = B
template<int C, int CO>
__global__ __launch_bounds__(256) void gemm_uw_kernel(const float* __restrict__ h,
    const float* __restrict__ W, float* __restrict__ ubuf, float* __restrict__ wbuf) {
  __shared__ float hs[C][128];
  __shared__ float Ws[64][C + 1];          // +1 pad: kill 32-way bank conflict
  const int b  = blockIdx.z;
  const int n0 = blockIdx.x * 128;
  const int which = blockIdx.y & 1;
  const int o0 = (blockIdx.y >> 1) * 64;
  const int tid = threadIdx.x;
  for (int i = tid; i < 64 * C; i += 256) {
    int o = i / C, c = i % C;
    const float* wr = W + (size_t)(o0 + o) * (2 * C);
    float w1 = wr[c];
    Ws[o][c] = which ? (wr[C + c] - w1) : w1;
  }
  const float* hb = h + (size_t)b * C * N_ + n0;
  for (int i = tid; i < C * 128; i += 256) {
    int c = i >> 7, nn = i & 127;
    hs[c][nn] = hb[(size_t)c * N_ + nn];
  }
  __syncthreads();
  const int ob = (tid & 15) * 4;
  const int nb = (tid >> 4) * 8;
  float acc[8][4];
  #pragma unroll
  for (int i = 0; i < 8; ++i)
    #pragma unroll
    for (int j = 0; j < 4; ++j) acc[i][j] = 0.f;
  for (int c = 0; c < C; ++c) {
    float hv[8];
    *(float4*)&hv[0] = *(const float4*)&hs[c][nb];
    *(float4*)&hv[4] = *(const float4*)&hs[c][nb + 4];
    float w0 = Ws[ob][c], w1 = Ws[ob + 1][c], w2 = Ws[ob + 2][c], w3 = Ws[ob + 3][c];
    #pragma unroll
    for (int i = 0; i < 8; ++i) {
      acc[i][0] = fmaf(hv[i], w0, acc[i][0]);
      acc[i][1] = fmaf(hv[i], w1, acc[i][1]);
      acc[i][2] = fmaf(hv[i], w2, acc[i][2]);
      acc[i][3] = fmaf(hv[i], w3, acc[i][3]);
    }
  }
  float* out = (which ? wbuf : ubuf) + ((size_t)(b * N_ + n0 + nb)) * CO + o0 + ob;
  #pragma unroll
  for (int i = 0; i < 8; ++i) {
    float4 v4; v4.x = acc[i][0]; v4.y = acc[i][1]; v4.z = acc[i][2]; v4.w = acc[i][3];
    *(float4*)(out + (size_t)i * CO) = v4;
  }
}

// ---------------- gather pass: per-(o,n) max/min over k + fp64 stats ----------------
template<int CO, int NSPLIT>
__global__ __launch_bounds__(256) void passA_kernel(const float* __restrict__ ubuf,
    const float* __restrict__ wbuf, const int* __restrict__ idxg,
    float* __restrict__ Mx, float* __restrict__ Mn, double* __restrict__ stats) {
  __shared__ float us[N_][32];             // 128 KB, gather reads conflict-free (o fastest)
  const int b = blockIdx.y;
  const int otile = blockIdx.x / NSPLIT;
  const int ns    = blockIdx.x % NSPLIT;
  const int o0 = otile * 32;
  constexpr int NSUB = N_ / NSPLIT;
  const int nstart = ns * NSUB;
  const int tid = threadIdx.x;
  const float* ub = ubuf + (size_t)b * N_ * CO + o0;
  for (int i = tid; i < N_ * 32; i += 256) {
    int n = i >> 5, o = i & 31;
    us[n][o] = ub[(size_t)n * CO + o];
  }
  __syncthreads();
  const int o = tid & 31, ng = tid >> 5;
  double s_y = 0.0, s_y2 = 0.0;
  const size_t bnc = (size_t)b * N_ * CO;
  for (int n = nstart + ng; n < nstart + NSUB; n += 8) {
    const int* ip = idxg + (size_t)(b * N_ + n) * K_;
    int js[20];
    #pragma unroll
    for (int q = 0; q < 5; ++q) {
      int4 t4 = ((const int4*)ip)[q];
      js[q * 4 + 0] = t4.x; js[q * 4 + 1] = t4.y;
      js[q * 4 + 2] = t4.z; js[q * 4 + 3] = t4.w;
    }
    float mx = -3.4e38f, mn = 3.4e38f, s1 = 0.f, s2 = 0.f;
    #pragma unroll
    for (int k = 0; k < 20; ++k) {
      float v = us[js[k]][o];
      mx = fmaxf(mx, v); mn = fminf(mn, v);
      s1 += v; s2 = fmaf(v, v, s2);
    }
    float wvv = wbuf[bnc + (size_t)n * CO + o0 + o];
    s_y  += (double)s1 + 20.0 * (double)wvv;
    s_y2 += (double)s2 + 2.0 * (double)wvv * (double)s1 + 20.0 * (double)wvv * (double)wvv;
    Mx[bnc + (size_t)n * CO + o0 + o] = mx;
    Mn[bnc + (size_t)n * CO + o0 + o] = mn;
  }
  __syncthreads();                          // us dead: reuse as reduction scratch
  double* sc = (double*)&us[0][0];
  sc[(o * 8 + ng) * 2]     = s_y;
  sc[(o * 8 + ng) * 2 + 1] = s_y2;
  __syncthreads();
  if (tid < 32) {
    double a = 0.0, c2 = 0.0;
    #pragma unroll
    for (int g = 0; g < 8; ++g) { a += sc[(tid * 8 + g) * 2]; c2 += sc[(tid * 8 + g) * 2 + 1]; }
    atomicAdd(&stats[(o0 + tid) * 2],     a);
    atomicAdd(&stats[(o0 + tid) * 2 + 1], c2);
  }
}

// ---------------- BN + LeakyReLU + (implicit max_k) + transpose to (B,C,N) ----------------
template<int CO>
__global__ __launch_bounds__(256) void passB_kernel(const float* __restrict__ Mx,
    const float* __restrict__ Mn, const float* __restrict__ wbuf,
    const double* __restrict__ stats, const float* __restrict__ gam,
    const float* __restrict__ bet, float* __restrict__ hout) {
  __shared__ float T[CO][65];
  __shared__ float a_s[CO], c_s[CO];
  const int b = blockIdx.y, n0 = blockIdx.x * 64;
  const int tid = threadIdx.x;
  const double CNT = (double)B_ * N_ * K_;
  for (int oo = tid; oo < CO; oo += 256) {
    double m  = stats[oo * 2] / CNT;
    double vv = stats[oo * 2 + 1] / CNT - m * m;
    float a = gam[oo] * rsqrtf((float)vv + 1e-5f);
    a_s[oo] = a;
    c_s[oo] = bet[oo] - a * (float)m;
  }
  __syncthreads();
  const size_t base = (size_t)(b * N_ + n0) * CO;
  for (int i = tid; i < 64 * CO; i += 256) {
    int nn = i / CO, oo = i % CO;
    float a = a_s[oo];
    size_t off = base + (size_t)nn * CO + oo;
    float selv = (a >= 0.f) ? Mx[off] : Mn[off];    // max_k commutes through monotone BN+LReLU
    float z = fmaf(a, selv + wbuf[off], c_s[oo]);
    T[oo][nn] = (z >= 0.f) ? z : 0.2f * z;
  }
  __syncthreads();
  float* hb = hout + (size_t)b * CO * N_ + n0;
  for (int i = tid; i < 64 * CO; i += 256) {
    int oo = i >> 6, nn = i & 63;
    hb[(size_t)oo * N_ + nn] = T[oo][nn];
  }
}

// ---------------- final layer: BN + LReLU + max over (n,k) ----------------
__global__ __launch_bounds__(256) void final_kernel(const float* __restrict__ Mx,
    const float* __restrict__ Mn, const float* __restrict__ wbuf,
    const double* __restrict__ stats, const float* __restrict__ gam,
    const float* __restrict__ bet, float* __restrict__ out) {
  const int b = blockIdx.x, o = threadIdx.x;   // 256 threads = CO
  const double CNT = (double)B_ * N_ * K_;
  double m  = stats[o * 2] / CNT;
  double vv = stats[o * 2 + 1] / CNT - m * m;
  float a = gam[o] * rsqrtf((float)vv + 1e-5f);
  float c = bet[o] - a * (float)m;
  const float* mp = ((a >= 0.f) ? Mx : Mn) + (size_t)b * N_ * 256 + o;
  const float* wp = wbuf + (size_t)b * N_ * 256 + o;
  float best = -3.4e38f;
  for (int n = 0; n < N_; ++n) {
    float z = fmaf(a, mp[(size_t)n * 256] + wp[(size_t)n * 256], c);
    z = (z >= 0.f) ? z : 0.2f * z;
    best = fmaxf(best, z);
  }
  out[b * 256 + o] = best;
}

__global__ void zero_stats(double* p) {
  int i = blockIdx.x * 256 + threadIdx.x;
  if (i < 2048) p[i] = 0.0;
}

extern "C" void kernel_launch(void* const* d_in, const int* in_sizes, int n_in,
                              void* d_out, int out_size, void* d_ws, size_t ws_size,
                              hipStream_t stream) {
  (void)in_sizes; (void)n_in; (void)out_size; (void)ws_size;
  const float* x  = (const float*)d_in[0];
  const float* W0 = (const float*)d_in[1];
  const float* g0 = (const float*)d_in[2];
  const float* b0 = (const float*)d_in[3];
  const float* W1 = (const float*)d_in[4];
  const float* g1 = (const float*)d_in[5];
  const float* b1 = (const float*)d_in[6];
  const float* W2 = (const float*)d_in[7];
  const float* g2 = (const float*)d_in[8];
  const float* b2 = (const float*)d_in[9];
  const float* W3 = (const float*)d_in[10];
  const float* g3 = (const float*)d_in[11];
  const float* b3 = (const float*)d_in[12];

  float* ws  = (float*)d_ws;
  float* u   = ws;                               // 16*1024*256
  float* w   = u  + (size_t)B_ * N_ * 256;
  float* Mx  = w  + (size_t)B_ * N_ * 256;
  float* Mn  = Mx + (size_t)B_ * N_ * 256;
  float* h0b = Mn + (size_t)B_ * N_ * 256;       // (B,<=128,N) ping
  float* h1b = h0b + (size_t)B_ * 128 * N_;      // pong
  float* xxv = h1b + (size_t)B_ * 128 * N_;      // B*N norms
  int*   idx = (int*)(xxv + B_ * N_);            // B*N*K
  double* stats = (double*)(idx + (size_t)B_ * N_ * K_);  // 4 * 512 doubles

  zero_stats<<<8, 256, 0, stream>>>(stats);

  // Layer 0: C=4, CO=64
  xx_kernel<4><<<B_ * N_ / 256, 256, 0, stream>>>(x, xxv);
  knn_kernel<4><<<dim3(64, B_), 256, 0, stream>>>(x, xxv, idx);
  gemm_uw_kernel<4, 64><<<dim3(8, 2, B_), 256, 0, stream>>>(x, W0, u, w);
  passA_kernel<64, 8><<<dim3(16, B_), 256, 0, stream>>>(u, w, idx, Mx, Mn, stats);
  passB_kernel<64><<<dim3(16, B_), 256, 0, stream>>>(Mx, Mn, w, stats, g0, b0, h0b);

  // Layer 1: C=64, CO=64
  xx_kernel<64><<<B_ * N_ / 256, 256, 0, stream>>>(h0b, xxv);
  knn_kernel<64><<<dim3(64, B_), 256, 0, stream>>>(h0b, xxv, idx);
  gemm_uw_kernel<64, 64><<<dim3(8, 2, B_), 256, 0, stream>>>(h0b, W1, u, w);
  passA_kernel<64, 8><<<dim3(16, B_), 256, 0, stream>>>(u, w, idx, Mx, Mn, stats + 512);
  passB_kernel<64><<<dim3(16, B_), 256, 0, stream>>>(Mx, Mn, w, stats + 512, g1, b1, h1b);

  // Layer 2: C=64, CO=128
  xx_kernel<64><<<B_ * N_ / 256, 256, 0, stream>>>(h1b, xxv);
  knn_kernel<64><<<dim3(64, B_), 256, 0, stream>>>(h1b, xxv, idx);
  gemm_uw_kernel<64, 128><<<dim3(8, 4, B_), 256, 0, stream>>>(h1b, W2, u, w);
  passA_kernel<128, 4><<<dim3(16, B_), 256, 0, stream>>>(u, w, idx, Mx, Mn, stats + 1024);
  passB_kernel<128><<<dim3(16, B_), 256, 0, stream>>>(Mx, Mn, w, stats + 1024, g2, b2, h0b);

  // Layer 3: C=128, CO=256
  xx_kernel<128><<<B_ * N_ / 256, 256, 0, stream>>>(h0b, xxv);
  knn_kernel<128><<<dim3(64, B_), 256, 0, stream>>>(h0b, xxv, idx);
  gemm_uw_kernel<128, 256><<<dim3(8, 8, B_), 256, 0, stream>>>(h0b, W3, u, w);
  passA_kernel<256, 2><<<dim3(16, B_), 256, 0, stream>>>(u, w, idx, Mx, Mn, stats + 1536);
  final_kernel<<<B_, 256, 0, stream>>>(Mx, Mn, w, stats + 1536, g3, b3, (float*)d_out);
}